// Round 1
// baseline (182.898 us; speedup 1.0000x reference)
//
#include <hip/hip_runtime.h>

#define T_N 256
#define O_N 64
#define K_N 16
#define HW_N (224 * 224)      // 50176
#define DM 768
#define DO 2048
#define OMEGA_F 1e-6f

// ---------------- Kernel 1: proj_obj = ME @ W_obj + b_obj ; proj_frame = ME @ W_frame + b_frame
// one thread per output element; K=768 inner loop. Total 45056 threads.
__global__ void proj_kernel(const float* __restrict__ me,
                            const float* __restrict__ Wo, const float* __restrict__ bo,
                            const float* __restrict__ Wf, const float* __restrict__ bf,
                            float* __restrict__ proj_obj, float* __restrict__ proj_frame) {
    int idx = blockIdx.x * blockDim.x + threadIdx.x;
    const int total_o = K_N * DO;  // 32768
    if (idx < total_o) {
        int k = idx / DO, j = idx - k * DO;
        const float* mrow = me + k * DM;
        float acc = bo[j];
        #pragma unroll 4
        for (int d = 0; d < DM; ++d) acc += mrow[d] * Wo[d * DO + j];
        proj_obj[idx] = acc;
    } else {
        int i2 = idx - total_o;
        if (i2 < K_N * DM) {
            int k = i2 / DM, j = i2 - k * DM;
            const float* mrow = me + k * DM;
            float acc = bf[j];
            #pragma unroll 4
            for (int d = 0; d < DM; ++d) acc += mrow[d] * Wf[d * DM + j];
            proj_frame[i2] = acc;
        }
    }
}

// ---------------- Kernel 2: per-frame histogram of labels 1..16
// one block (256 threads) per frame; per-thread private LDS bins (no atomics).
__global__ __launch_bounds__(256) void hist_kernel(const int* __restrict__ masks,
                                                   float* __restrict__ counts) {
    __shared__ int bins[256 * 17];
    const int t = blockIdx.x;
    const int tid = threadIdx.x;
    int* my = &bins[tid * 17];
    #pragma unroll
    for (int i = 0; i < 17; ++i) my[i] = 0;

    const int4* p = (const int4*)(masks + (size_t)t * HW_N);
    const int n4 = HW_N / 4;  // 12544
    for (int i = tid; i < n4; i += 256) {
        int4 v = p[i];
        my[v.x]++; my[v.y]++; my[v.z]++; my[v.w]++;
    }
    __syncthreads();
    // reduce columns 1..16 across the 256 private rows
    if (tid < 16) {
        int s = 0;
        for (int r = 0; r < 256; ++r) s += bins[r * 17 + (tid + 1)];
        counts[t * K_N + tid] = (float)s;
    }
}

// ---------------- Kernel 3: obj_out = obj_feat + gamma * proj_obj[entity-1]  (or copy)
// one block per (t,o) row of 2048 floats; float4 path. proj_obj (128KB) lives in L2.
__global__ __launch_bounds__(256) void obj_kernel(const float* __restrict__ obj_feat,
                                                  const int* __restrict__ obj_entity,
                                                  const float* __restrict__ proj_obj,
                                                  const float* __restrict__ gamma,
                                                  float* __restrict__ out) {
    const int row = blockIdx.x;                 // t*64 + o
    const int e = obj_entity[row];              // scalar broadcast
    const float g = gamma[0];
    const float4* src = (const float4*)(obj_feat + (size_t)row * DO);
    float4* dst = (float4*)(out + (size_t)row * DO);
    const int n4 = DO / 4;                      // 512
    if (e > 0) {
        const float4* pr = (const float4*)(proj_obj + (size_t)(e - 1) * DO);
        for (int i = threadIdx.x; i < n4; i += 256) {
            float4 a = src[i];
            float4 b = pr[i];
            dst[i] = make_float4(a.x + g * b.x, a.y + g * b.y,
                                 a.z + g * b.z, a.w + g * b.w);
        }
    } else {
        for (int i = threadIdx.x; i < n4; i += 256) {
            dst[i] = src[i];
        }
    }
}

// ---------------- Kernel 4: frame_out = frame_feat + gamma * (counts @ proj_frame) / (omega + sum counts)
// one block (768 threads) per frame.
__global__ __launch_bounds__(768) void frame_kernel(const float* __restrict__ frame_feat,
                                                    const float* __restrict__ counts,
                                                    const float* __restrict__ proj_frame,
                                                    const float* __restrict__ gamma,
                                                    float* __restrict__ out_frame) {
    const int t = blockIdx.x;
    const int j = threadIdx.x;      // 0..767
    __shared__ float c[K_N];
    if (j < K_N) c[j] = counts[t * K_N + j];
    __syncthreads();
    float acc = 0.f, tot = 0.f;
    #pragma unroll
    for (int k = 0; k < K_N; ++k) {
        acc += c[k] * proj_frame[k * DM + j];
        tot += c[k];
    }
    const float g = gamma[0];
    out_frame[t * DM + j] = frame_feat[t * DM + j] + g * acc / (OMEGA_F + tot);
}

extern "C" void kernel_launch(void* const* d_in, const int* in_sizes, int n_in,
                              void* d_out, int out_size, void* d_ws, size_t ws_size,
                              hipStream_t stream) {
    const float* obj_feat   = (const float*)d_in[0];   // [T,O,DO]
    const float* frame_feat = (const float*)d_in[1];   // [T,DM]
    const float* me         = (const float*)d_in[2];   // [K,DM]
    const int*   obj_entity = (const int*)d_in[3];     // [T,O]
    const int*   masks      = (const int*)d_in[4];     // [T,H,W]
    const float* Wo         = (const float*)d_in[5];   // [DM,DO]
    const float* bo         = (const float*)d_in[6];   // [DO]
    const float* Wf         = (const float*)d_in[7];   // [DM,DM]
    const float* bf         = (const float*)d_in[8];   // [DM]
    const float* gamma      = (const float*)d_in[9];   // scalar

    float* obj_out   = (float*)d_out;                          // [T,O,DO]
    float* frame_out = (float*)d_out + (size_t)T_N * O_N * DO; // [T,DM]

    float* ws = (float*)d_ws;
    float* proj_obj   = ws;                  // 16*2048 = 32768 floats
    float* proj_frame = ws + 32768;          // 16*768  = 12288 floats
    float* counts     = ws + 32768 + 12288;  // 256*16  = 4096 floats

    // 1) projections (tiny GEMMs)
    {
        int total = K_N * DO + K_N * DM;  // 45056
        int blocks = (total + 255) / 256;
        proj_kernel<<<blocks, 256, 0, stream>>>(me, Wo, bo, Wf, bf, proj_obj, proj_frame);
    }
    // 2) per-frame mask histogram
    hist_kernel<<<T_N, 256, 0, stream>>>(masks, counts);
    // 3) object injection (dominant, memory-bound)
    obj_kernel<<<T_N * O_N, 256, 0, stream>>>(obj_feat, obj_entity, proj_obj, gamma, obj_out);
    // 4) frame injection
    frame_kernel<<<T_N, 768, 0, stream>>>(frame_feat, counts, proj_frame, gamma, frame_out);
}

// Round 2
// 88.921 us; speedup vs baseline: 2.0569x; 2.0569x over previous
//
#include <hip/hip_runtime.h>

#define T_N 256
#define O_N 64
#define K_N 16
#define HW_N (224 * 224)      // 50176
#define DM 768
#define DO 2048
#define OMEGA_F 1e-6f

// ---------------- Kernel 1: split-K tile GEMM for both projections.
// Each block: 64 output columns x 8 K-segments (512 threads).
// me (16x768 = 48KB) staged in LDS; W streamed coalesced, 16 FMA per loaded word.
#define PCOLS 64
#define PSEG 8
#define PDSEG (DM / PSEG)     // 96

__global__ __launch_bounds__(512) void proj_kernel2(const float* __restrict__ me,
                                                    const float* __restrict__ Wo, const float* __restrict__ bo,
                                                    const float* __restrict__ Wf, const float* __restrict__ bf,
                                                    float* __restrict__ proj_obj, float* __restrict__ proj_frame) {
    __shared__ float me_lds[K_N * DM];             // 48 KB
    __shared__ float partial[PSEG][K_N][PCOLS];    // 32 KB
    const int tid = threadIdx.x;

    for (int i = tid; i < K_N * DM; i += 512) me_lds[i] = me[i];
    __syncthreads();

    const int NB_O = DO / PCOLS;  // 32
    const int b = blockIdx.x;
    const float* W; const float* bias; float* out; int ld; int j0;
    if (b < NB_O) { W = Wo; bias = bo; out = proj_obj;   ld = DO; j0 = b * PCOLS; }
    else          { W = Wf; bias = bf; out = proj_frame; ld = DM; j0 = (b - NB_O) * PCOLS; }

    const int jj = tid & (PCOLS - 1);
    const int s  = tid >> 6;               // 0..7, uniform per wave
    const int j  = j0 + jj;

    float acc[K_N];
    #pragma unroll
    for (int k = 0; k < K_N; ++k) acc[k] = 0.f;

    const int d0 = s * PDSEG;
    #pragma unroll 4
    for (int d = d0; d < d0 + PDSEG; ++d) {
        float w = W[(size_t)d * ld + j];   // coalesced across 64 lanes
        #pragma unroll
        for (int k = 0; k < K_N; ++k) acc[k] += me_lds[k * DM + d] * w;  // LDS broadcast
    }
    #pragma unroll
    for (int k = 0; k < K_N; ++k) partial[s][k][jj] = acc[k];
    __syncthreads();

    // reduce 8 segments -> 16x64 outputs, 512 threads handle 2 each
    for (int o = tid; o < K_N * PCOLS; o += 512) {
        int k = o >> 6, c = o & 63;
        float ssum = 0.f;
        #pragma unroll
        for (int s2 = 0; s2 < PSEG; ++s2) ssum += partial[s2][k][c];
        out[k * ld + j0 + c] = ssum + bias[j0 + c];
    }
}

// ---------------- Kernel 2: per-frame histogram, 4 sub-blocks per frame.
#define SUBB 4
__global__ __launch_bounds__(256) void hist_kernel(const int* __restrict__ masks,
                                                   float* __restrict__ counts_partial) {
    __shared__ int bins[256 * 17];
    __shared__ int partial2[16][17];
    const int blk = blockIdx.x;
    const int t = blk / SUBB, sub = blk % SUBB;
    const int tid = threadIdx.x;
    int* my = &bins[tid * 17];
    #pragma unroll
    for (int i = 0; i < 17; ++i) my[i] = 0;

    const int4* p = (const int4*)(masks + (size_t)t * HW_N);
    const int n4 = HW_N / 4;          // 12544
    const int chunk = n4 / SUBB;      // 3136
    const int end = (sub + 1) * chunk;
    for (int i = sub * chunk + tid; i < end; i += 256) {
        int4 v = p[i];
        my[v.x]++; my[v.y]++; my[v.z]++; my[v.w]++;
    }
    __syncthreads();
    // two-stage reduce of bins 1..16 across 256 private rows
    const int bcol = tid & 15, rg = tid >> 4;
    int ssum = 0;
    #pragma unroll
    for (int r = 0; r < 16; ++r) ssum += bins[(rg * 16 + r) * 17 + (bcol + 1)];
    partial2[rg][bcol] = ssum;
    __syncthreads();
    if (tid < 16) {
        int s = 0;
        #pragma unroll
        for (int r = 0; r < 16; ++r) s += partial2[r][tid];
        counts_partial[((size_t)sub * T_N + t) * K_N + tid] = (float)s;
    }
}

// ---------------- Kernel 3: obj_out = obj_feat + gamma * proj_obj[entity-1]  (or copy)
__global__ __launch_bounds__(256) void obj_kernel(const float* __restrict__ obj_feat,
                                                  const int* __restrict__ obj_entity,
                                                  const float* __restrict__ proj_obj,
                                                  const float* __restrict__ gamma,
                                                  float* __restrict__ out) {
    const int row = blockIdx.x;                 // t*64 + o
    const int e = obj_entity[row];              // scalar broadcast
    const float g = gamma[0];
    const float4* src = (const float4*)(obj_feat + (size_t)row * DO);
    float4* dst = (float4*)(out + (size_t)row * DO);
    const int n4 = DO / 4;                      // 512
    if (e > 0) {
        const float4* pr = (const float4*)(proj_obj + (size_t)(e - 1) * DO);
        for (int i = threadIdx.x; i < n4; i += 256) {
            float4 a = src[i];
            float4 b = pr[i];
            dst[i] = make_float4(a.x + g * b.x, a.y + g * b.y,
                                 a.z + g * b.z, a.w + g * b.w);
        }
    } else {
        for (int i = threadIdx.x; i < n4; i += 256) {
            dst[i] = src[i];
        }
    }
}

// ---------------- Kernel 4: frame_out = frame_feat + gamma*(counts@proj_frame)/(omega+sum)
__global__ __launch_bounds__(768) void frame_kernel(const float* __restrict__ frame_feat,
                                                    const float* __restrict__ counts_partial,
                                                    const float* __restrict__ proj_frame,
                                                    const float* __restrict__ gamma,
                                                    float* __restrict__ out_frame) {
    const int t = blockIdx.x;
    const int j = threadIdx.x;      // 0..767
    __shared__ float c[K_N];
    if (j < K_N) {
        float s = 0.f;
        #pragma unroll
        for (int sb = 0; sb < SUBB; ++sb)
            s += counts_partial[((size_t)sb * T_N + t) * K_N + j];
        c[j] = s;
    }
    __syncthreads();
    float acc = 0.f, tot = 0.f;
    #pragma unroll
    for (int k = 0; k < K_N; ++k) {
        acc += c[k] * proj_frame[k * DM + j];
        tot += c[k];
    }
    const float g = gamma[0];
    out_frame[t * DM + j] = frame_feat[t * DM + j] + g * acc / (OMEGA_F + tot);
}

extern "C" void kernel_launch(void* const* d_in, const int* in_sizes, int n_in,
                              void* d_out, int out_size, void* d_ws, size_t ws_size,
                              hipStream_t stream) {
    const float* obj_feat   = (const float*)d_in[0];   // [T,O,DO]
    const float* frame_feat = (const float*)d_in[1];   // [T,DM]
    const float* me         = (const float*)d_in[2];   // [K,DM]
    const int*   obj_entity = (const int*)d_in[3];     // [T,O]
    const int*   masks      = (const int*)d_in[4];     // [T,H,W]
    const float* Wo         = (const float*)d_in[5];   // [DM,DO]
    const float* bo         = (const float*)d_in[6];   // [DO]
    const float* Wf         = (const float*)d_in[7];   // [DM,DM]
    const float* bf         = (const float*)d_in[8];   // [DM]
    const float* gamma      = (const float*)d_in[9];   // scalar

    float* obj_out   = (float*)d_out;                          // [T,O,DO]
    float* frame_out = (float*)d_out + (size_t)T_N * O_N * DO; // [T,DM]

    float* ws = (float*)d_ws;
    float* proj_obj      = ws;                  // 16*2048 = 32768 floats
    float* proj_frame    = ws + 32768;          // 16*768  = 12288 floats
    float* counts_partial= ws + 32768 + 12288;  // 4*256*16 = 16384 floats

    // 1) projections (split-K tile GEMM): 32 obj-col blocks + 12 frame-col blocks
    proj_kernel2<<<DO / PCOLS + DM / PCOLS, 512, 0, stream>>>(
        me, Wo, bo, Wf, bf, proj_obj, proj_frame);
    // 2) per-frame mask histogram (4 sub-blocks per frame)
    hist_kernel<<<T_N * SUBB, 256, 0, stream>>>(masks, counts_partial);
    // 3) object injection (dominant, memory-bound)
    obj_kernel<<<T_N * O_N, 256, 0, stream>>>(obj_feat, obj_entity, proj_obj, gamma, obj_out);
    // 4) frame injection
    frame_kernel<<<T_N, 768, 0, stream>>>(frame_feat, counts_partial, proj_frame, gamma, frame_out);
}